// Round 9
// baseline (477.075 us; speedup 1.0000x reference)
//
#include <hip/hip_runtime.h>
#include <math.h>

// Problem: N=8, C=1, H=W=512 fp32. 16 images (8 sigmoid + 8 target) skeletonized.
#define IMG   512
#define NSAMP 8
#define NIMG  16
#define PS    (IMG * IMG)

#define NBANDS 32
#define BH     (IMG / NBANDS)   // 16  (R0 even -> static parities)
#define HALO   8                // column halo (cols, even); needs >= C+1
#define OW     112              // owned cols/wave = 128 - 2*HALO
#define NSTRIP 5                // ceil(512/112)

__device__ __forceinline__ float sigm(float x) { return 1.0f / (1.0f + expf(-x)); }

// DPP lane shifts (verified direction via AMD scan idiom: SHR reads lane i-1):
//   dpp_a(x)[i] = x[i+1] (right neighbor), dpp_b(x)[i] = x[i-1] (left neighbor).
// Shifted-in lanes -> 0; garbage contained in the HALO column ring.
__device__ __forceinline__ float dpp_a(float x) {
#if __has_builtin(__builtin_amdgcn_update_dpp)
    return __int_as_float(__builtin_amdgcn_update_dpp(0, __float_as_int(x),
                                                      0x130, 0xF, 0xF, true)); // WAVE_SHL1
#else
    return __shfl_down(x, 1, 64);
#endif
}
__device__ __forceinline__ float dpp_b(float x) {
#if __has_builtin(__builtin_amdgcn_update_dpp)
    return __int_as_float(__builtin_amdgcn_update_dpp(0, __float_as_int(x),
                                                      0x138, 0xF, 0xF, true)); // WAVE_SHR1
#else
    return __shfl_up(x, 1, 64);
#endif
}

// ---- prep: X[0:n]=sigmoid(logits), X[n:2n]=target ----
__global__ __launch_bounds__(256) void prep_kernel(const float4* __restrict__ lg,
                                                   const float4* __restrict__ tg,
                                                   float4* __restrict__ X, int n4)
{
    int i = blockIdx.x * 256 + threadIdx.x;
    if (i < n4) {
        float4 L = lg[i];
        X[i]      = make_float4(sigm(L.x), sigm(L.y), sigm(L.z), sigm(L.w));
        X[i + n4] = tg[i];
    }
}

// ---- register line-pipeline, 2 COLS/LANE, 1 row/step, C fused levels, no LDS ----
// R8 post-mortem: SIMD retires wave-steps at a fixed ~630 cyc/slot regardless of
// resident waves (>=2/SIMD) -> minimize wave-steps: 128 cols/wave via float2.
// Pair-interior horizontal neighbors are in-register; only pair-boundary
// exchange uses DPP (4/level for 2 cols). HALO=8 even -> pair-uniform colOK,
// aligned dwordx2 loads/stores, owned lanes [4,60).
// NOTE (R6): never cap occupancy via __launch_bounds__ 2nd arg (spill disaster).
template<int C, bool ER, bool EC, bool INIT, bool LAST>
__device__ __forceinline__ void pipe_run(const float* __restrict__ xg,
                                         float* __restrict__ xo,
                                         float* __restrict__ Sg,
                                         int R0, int gc, bool colOK, bool owned)
{
    const float INF = __builtin_inff();
    constexpr int RAW    = BH + 2 * C + 2;
    constexpr int INNER  = (C % 2 == 0) ? C : 2 * C;
    constexpr int NSTEPS = ((RAW + INNER - 1) / INNER) * INNER;
    constexpr int PAD    = NSTEPS - RAW;
    constexpr int T0PAR  = (C + 1 + PAD) & 1;     // parity of t0 (R0 even)
    constexpr int XS0    = 2 * C + 1 + PAD;       // k-window start for x stores
    constexpr int SS0    = 2 * C + 2 + PAD;       // k-window start for skel stores
    const int t0 = R0 - C - 1 - PAD;

    float W0[C][2], W1[C][2], HM0[C][2], HM1[C][2];
    float SK0[C], SK1[C], XQ0[C], XQ1[C], SQ0[C], SQ1[C];
    #pragma unroll
    for (int l = 0; l < C; ++l) {
        W0[l][0] = INF;  W0[l][1] = INF;  W1[l][0] = INF;  W1[l][1] = INF;
        HM0[l][0] = -INF; HM0[l][1] = -INF; HM1[l][0] = -INF; HM1[l][1] = -INF;
        SK0[l] = 0.f; SK1[l] = 0.f;
    }

    const float* xp = xg + gc;
    float* sp = Sg + gc;
    float* op = xo + gc;

    auto xld = [&](int r) -> float2 {
        if (ER || EC) {
            bool ok = (!ER || (unsigned)r < (unsigned)IMG) && (!EC || colOK);
            float2 v = make_float2(INF, INF);
            if (ok) v = *(const float2*)(xp + r * IMG);
            return v;
        }
        return *(const float2*)(xp + r * IMG);   // interior: provably in-bounds
    };
    auto sld = [&](int r) -> float2 {
        if (INIT) return make_float2(0.f, 0.f);
        if (ER || EC) {
            bool ok = (!ER || (unsigned)r < (unsigned)IMG) && (!EC || colOK);
            float2 v = make_float2(0.f, 0.f);
            if (ok) v = *(const float2*)(sp + r * IMG);
            return v;
        }
        return *(const float2*)(sp + r * IMG);
    };

    #pragma unroll
    for (int i = 0; i < C; ++i) { float2 v = xld(t0 + i); XQ0[i] = v.x; XQ1[i] = v.y; }
    #pragma unroll
    for (int i = 0; i < C; ++i) {
        float2 v = INIT ? make_float2(0.f, 0.f) : sld(t0 - 1 + i);
        SQ0[i] = v.x; SQ1[i] = v.y;
    }

    for (int kk = 0; kk < NSTEPS; kk += INNER) {       // rolled outer loop
        #pragma unroll
        for (int j = 0; j < INNER; ++j) {              // fully unrolled: j static
            const int k = kk + j;
            const int t = t0 + k;
            const int qi = j % C;                      // static
            float Cin0 = XQ0[qi], Cin1 = XQ1[qi];      // x_0 row t
            { float2 nv = xld(t + C); XQ0[qi] = nv.x; XQ1[qi] = nv.y; }
            float sn0 = SQ0[qi], sn1 = SQ1[qi];        // s row t-1
            if (!INIT) { float2 sv = sld(t + C - 1); SQ0[qi] = sv.x; SQ1[qi] = sv.y; }

            #pragma unroll
            for (int l = 0; l < C; ++l) {
                const int bp = (T0PAR + j + l + 1) & 1;  // parity of row t-l-1
                float A0 = W0[l][bp ^ 1], B0 = W0[l][bp];
                float A1 = W1[l][bp ^ 1], B1 = W1[l][bp];
                // erode (cross): col0 neighbors = (left-lane col1, own col1);
                //                col1 neighbors = (own col0, right-lane col0)
                float e0 = fminf(fminf(A0, Cin0), B0);
                float e1 = fminf(fminf(A1, Cin1), B1);
                e0 = fminf(e0, fminf(dpp_b(B1), B1));
                e1 = fminf(e1, fminf(B0, dpp_a(B0)));
                if (ER) {
                    bool rok = (unsigned)(t - l - 1) < (unsigned)IMG;
                    e0 = rok ? e0 : INF;  e1 = rok ? e1 : INF;
                }
                float xd0 = e0, xd1 = e1;
                if (EC) {                    // pair-uniform column forcing
                    xd0 = colOK ? e0 : -INF;  e0 = colOK ? e0 : INF;
                    xd1 = colOK ? e1 : -INF;  e1 = colOK ? e1 : INF;
                }
                float hm0 = fmaxf(fmaxf(dpp_b(xd1), xd0), xd1);
                float hm1 = fmaxf(fmaxf(xd0, xd1), dpp_a(xd0));
                if (ER) {
                    bool rok = (unsigned)(t - l - 1) < (unsigned)IMG;
                    hm0 = rok ? hm0 : -INF;  hm1 = rok ? hm1 : -INF;
                }
                float dil0 = fmaxf(fmaxf(HM0[l][bp], HM0[l][bp ^ 1]), hm0);
                float dil1 = fmaxf(fmaxf(HM1[l][bp], HM1[l][bp ^ 1]), hm1);
                float d0 = fmaxf(A0 - dil0, 0.f);
                float d1 = fmaxf(A1 - dil1, 0.f);
                const int si = (l + C - qi) % C;         // SK slot of stage l (static)
                float s0 = SK0[si]; SK0[si] = (s0 + d0) - s0 * d0;
                float s1 = SK1[si]; SK1[si] = (s1 + d1) - s1 * d1;
                W0[l][bp ^ 1] = Cin0;  W1[l][bp ^ 1] = Cin1;
                HM0[l][bp] = hm0;      HM1[l][bp] = hm1;
                Cin0 = e0;  Cin1 = e1;                   // feed next level
            }

            // stores: x_C row t-C, skel row t-C-1 (wave-uniform k-guards)
            if (!LAST) {
                if ((unsigned)(k - XS0) < BH) {
                    if (owned) *(float2*)(op + (t - C) * IMG) = make_float2(Cin0, Cin1);
                }
            }
            if ((unsigned)(k - SS0) < BH) {
                const int so = (2 * C - 1 - qi) % C;     // stage C-1 slot (static)
                if (owned) *(float2*)(sp + (t - C - 1) * IMG) = make_float2(SK0[so], SK1[so]);
            }
            // insert s[t-1] at next step's stage-0 slot (== retiring stage C-1 slot)
            const int ins = (C - ((j + 1) % C)) % C;
            SK0[ins] = sn0;  SK1[ins] = sn1;
        }
    }
}

template<int C, bool INIT, bool LAST>
__global__ __launch_bounds__(256) void fused_pipe(const float* __restrict__ xin,
                                                  float* __restrict__ xout,
                                                  float* __restrict__ S)
{
    const int lane = threadIdx.x & 63;
    const int task = blockIdx.x * 4 + (threadIdx.x >> 6);
    const int strip = task % NSTRIP;
    const int rem = task / NSTRIP;
    const int band = rem % NBANDS;
    const int img = rem / NBANDS;
    const int R0 = band * BH;
    const int gc = strip * OW - HALO + 2 * lane;         // even; lane owns (gc, gc+1)
    const bool colOK = (unsigned)gc < (unsigned)IMG;     // pair-uniform
    const bool owned = (lane >= HALO / 2) && (lane < 64 - HALO / 2) && colOK;
    const float* xg = xin + (size_t)img * PS;
    float* xo = xout + (size_t)img * PS;
    float* Sg = S + (size_t)img * PS;
    const bool erow = (band == 0) || (band == NBANDS - 1);
    const bool ecol = (strip == 0) || (strip * OW - HALO + 127 >= IMG);

    if (erow) {
        if (ecol) pipe_run<C, true , true , INIT, LAST>(xg, xo, Sg, R0, gc, colOK, owned);
        else      pipe_run<C, true , false, INIT, LAST>(xg, xo, Sg, R0, gc, colOK, owned);
    } else {
        if (ecol) pipe_run<C, false, true , INIT, LAST>(xg, xo, Sg, R0, gc, colOK, owned);
        else      pipe_run<C, false, false, INIT, LAST>(xg, xo, Sg, R0, gc, colOK, owned);
    }
}

// ---- reduction: per-block partials, no global atomics ----
__global__ __launch_bounds__(256) void reduce_kernel(const float* __restrict__ logits,
                                                     const float* __restrict__ target,
                                                     const float* __restrict__ S,
                                                     float* __restrict__ partial)
{
    const int sample = blockIdx.y;
    const size_t base = (size_t)sample * PS;
    const float4* p4  = (const float4*)(logits + base);
    const float4* t4  = (const float4*)(target + base);
    const float4* sp4 = (const float4*)(S + base);
    const float4* sl4 = (const float4*)(S + (size_t)NSAMP * PS + base);
    float v[7] = {0.f, 0.f, 0.f, 0.f, 0.f, 0.f, 0.f};
    const int n4 = PS / 4;
    for (int i = blockIdx.x * 256 + threadIdx.x; i < n4; i += 32 * 256) {
        float4 L = p4[i], Tt = t4[i], SP = sp4[i], SL = sl4[i];
        float p;
        p = sigm(L.x); v[0] += SP.x * Tt.x; v[1] += SP.x; v[2] += SL.x * p; v[3] += SL.x; v[4] += p * Tt.x; v[5] += p; v[6] += Tt.x;
        p = sigm(L.y); v[0] += SP.y * Tt.y; v[1] += SP.y; v[2] += SL.y * p; v[3] += SL.y; v[4] += p * Tt.y; v[5] += p; v[6] += Tt.y;
        p = sigm(L.z); v[0] += SP.z * Tt.z; v[1] += SP.z; v[2] += SL.z * p; v[3] += SL.z; v[4] += p * Tt.z; v[5] += p; v[6] += Tt.z;
        p = sigm(L.w); v[0] += SP.w * Tt.w; v[1] += SP.w; v[2] += SL.w * p; v[3] += SL.w; v[4] += p * Tt.w; v[5] += p; v[6] += Tt.w;
    }
    #pragma unroll
    for (int off = 32; off > 0; off >>= 1)
        #pragma unroll
        for (int q = 0; q < 7; ++q) v[q] += __shfl_down(v[q], off);
    __shared__ float wred[4][7];
    int lane = threadIdx.x & 63, w = threadIdx.x >> 6;
    if (lane == 0)
        #pragma unroll
        for (int q = 0; q < 7; ++q) wred[w][q] = v[q];
    __syncthreads();
    if (threadIdx.x == 0) {
        #pragma unroll
        for (int q = 0; q < 7; ++q)
            partial[(sample * 32 + blockIdx.x) * 7 + q] =
                wred[0][q] + wred[1][q] + wred[2][q] + wred[3][q];
    }
}

__global__ __launch_bounds__(256) void final_kernel(const float* __restrict__ partial,
                                                    float* __restrict__ out)
{
    const int t = threadIdx.x;
    const int sample = t >> 5, part = t & 31;
    float v[7];
    #pragma unroll
    for (int q = 0; q < 7; ++q) v[q] = partial[(sample * 32 + part) * 7 + q];
    #pragma unroll
    for (int off = 16; off > 0; off >>= 1)
        #pragma unroll
        for (int q = 0; q < 7; ++q) v[q] += __shfl_down(v[q], off, 32);
    __shared__ float acc[NSAMP][7];
    if (part == 0)
        #pragma unroll
        for (int q = 0; q < 7; ++q) acc[sample][q] = v[q];
    __syncthreads();
    if (t == 0) {
        float cl = 0.f, dice = 0.f;
        for (int n = 0; n < NSAMP; n++) {
            float A = acc[n][0], Bv = acc[n][1], Cc = acc[n][2], D = acc[n][3];
            float E = acc[n][4], F = acc[n][5], G = acc[n][6];
            float tprec = (A + 1.0f) / (Bv + 1.0f);
            float tsens = (Cc + 1.0f) / (D + 1.0f);
            cl   += 1.0f - 2.0f * tprec * tsens / (tprec + tsens);
            dice += 1.0f - 2.0f * (E + 1.0f) / (F + G + 1.0f);
        }
        out[0] = 0.7f * (dice / NSAMP) + 0.3f * (cl / NSAMP);
    }
}

extern "C" void kernel_launch(void* const* d_in, const int* in_sizes, int n_in,
                              void* d_out, int out_size, void* d_ws, size_t ws_size,
                              hipStream_t stream)
{
    const float* logits = (const float*)d_in[0];
    const float* target = (const float*)d_in[1];
    float* out = (float*)d_out;

    const size_t NTOT = (size_t)NIMG * PS;
    float* Xa = (float*)d_ws;                       // Xa | Xb | S | partial
    float* Xb = Xa + NTOT;
    float* S  = Xb + NTOT;
    float* partial = S + NTOT;                      // 256*7 floats

    const int n4 = (NSAMP * PS) / 4;
    prep_kernel<<<n4 / 256, 256, 0, stream>>>((const float4*)logits, (const float4*)target,
                                              (float4*)Xa, n4);

    // 51 levels = 6 (INIT) + 7*6 + 3 (LAST). grid = NSTRIP*NBANDS*NIMG/4 = 640 blocks.
    const int B = NSTRIP * NBANDS * NIMG / 4;       // 640 blocks (2560 waves)
    fused_pipe<6, true , false><<<B, 256, 0, stream>>>(Xa, Xb, S);
    fused_pipe<6, false, false><<<B, 256, 0, stream>>>(Xb, Xa, S);
    fused_pipe<6, false, false><<<B, 256, 0, stream>>>(Xa, Xb, S);
    fused_pipe<6, false, false><<<B, 256, 0, stream>>>(Xb, Xa, S);
    fused_pipe<6, false, false><<<B, 256, 0, stream>>>(Xa, Xb, S);
    fused_pipe<6, false, false><<<B, 256, 0, stream>>>(Xb, Xa, S);
    fused_pipe<6, false, false><<<B, 256, 0, stream>>>(Xa, Xb, S);
    fused_pipe<6, false, false><<<B, 256, 0, stream>>>(Xb, Xa, S);
    fused_pipe<3, false, true ><<<B, 256, 0, stream>>>(Xa, Xb, S);   // last: skip dead x-write

    reduce_kernel<<<dim3(32, NSAMP), 256, 0, stream>>>(logits, target, S, partial);
    final_kernel<<<1, 256, 0, stream>>>(partial, out);
}

// Round 10
// 466.235 us; speedup vs baseline: 1.0232x; 1.0232x over previous
//
#include <hip/hip_runtime.h>
#include <math.h>

// Problem: N=8, C=1, H=W=512 fp32. 16 images (8 sigmoid + 8 target) skeletonized.
#define IMG   512
#define NSAMP 8
#define NIMG  16
#define PS    (IMG * IMG)
#define IOFF  (NSAMP * PS)      // offset between paired images (img i and i+8)

#define NBANDS 32
#define BH     (IMG / NBANDS)   // 16 (R0 even -> static parities; PAD=0 for C=6,3)
#define NPAIR  8                // image pairs per launch

__device__ __forceinline__ float sigm(float x) { return 1.0f / (1.0f + expf(-x)); }

// cross-lane shift by 1 at VALU rate (DPP). Stencils are L/R symmetric, so the
// direction ambiguity is harmless. Shifted-in lanes -> 0; garbage stays in the
// (C+1)-lane column halo.
__device__ __forceinline__ float dpp_a(float x) {
#if __has_builtin(__builtin_amdgcn_update_dpp)
    return __int_as_float(__builtin_amdgcn_update_dpp(0, __float_as_int(x),
                                                      0x130, 0xF, 0xF, true)); // WAVE_SHL1
#else
    return __shfl_down(x, 1, 64);
#endif
}
__device__ __forceinline__ float dpp_b(float x) {
#if __has_builtin(__builtin_amdgcn_update_dpp)
    return __int_as_float(__builtin_amdgcn_update_dpp(0, __float_as_int(x),
                                                      0x138, 0xF, 0xF, true)); // WAVE_SHR1
#else
    return __shfl_up(x, 1, 64);
#endif
}

// ---- prep: X[0:n]=sigmoid(logits), X[n:2n]=target ----
__global__ __launch_bounds__(256) void prep_kernel(const float4* __restrict__ lg,
                                                   const float4* __restrict__ tg,
                                                   float4* __restrict__ X, int n4)
{
    int i = blockIdx.x * 256 + threadIdx.x;
    if (i < n4) {
        float4 L = lg[i];
        X[i]      = make_float4(sigm(L.x), sigm(L.y), sigm(L.z), sigm(L.w));
        X[i + n4] = tg[i];
    }
}

// ---- register line-pipeline, TWO INDEPENDENT IMAGES per wave, 1 col/lane ----
// R8/R9 calibration: SIMD retires ~630 cyc/wave-step at >=2.5 waves/SIMD with
// VALUBusy only ~43% (TLP doesn't fill the idle); R9's coupled dual-column
// chains inflated the slot 2.6x. Here each wave runs two fully-independent
// pipelines (image i and i+8: same geometry, zero cross-image dataflow) to
// fill the per-step idle with clean ILP while wave-steps drop 0.65x.
// NOTE (R6): never cap occupancy via __launch_bounds__ 2nd arg (spill disaster).
template<int C, bool ER, bool EC, bool INIT, bool LAST>
__device__ __forceinline__ void pipe_run(const float* __restrict__ xg,
                                         float* __restrict__ xo,
                                         float* __restrict__ Sg,
                                         int R0, int gcol, bool colOK, bool owned)
{
    const float INF = __builtin_inff();
    constexpr int RAW    = BH + 2 * C + 2;
    constexpr int INNER  = (C % 2 == 0) ? C : 2 * C;
    constexpr int NSTEPS = ((RAW + INNER - 1) / INNER) * INNER;
    constexpr int PAD    = NSTEPS - RAW;
    constexpr int T0PAR  = (C + 1 + PAD) & 1;     // parity of t0 (R0 even)
    constexpr int XS0    = 2 * C + 1 + PAD;       // k-window start for x stores
    constexpr int SS0    = 2 * C + 2 + PAD;       // k-window start for skel stores
    const int t0 = R0 - C - 1 - PAD;

    float Wa[C][2], Wb[C][2], Ha[C][2], Hb[C][2];
    float SKa[C], SKb[C], XQa[C], XQb[C], SQa[C], SQb[C];
    #pragma unroll
    for (int l = 0; l < C; ++l) {
        Wa[l][0] = INF;  Wa[l][1] = INF;  Wb[l][0] = INF;  Wb[l][1] = INF;
        Ha[l][0] = -INF; Ha[l][1] = -INF; Hb[l][0] = -INF; Hb[l][1] = -INF;
        SKa[l] = 0.f; SKb[l] = 0.f;
    }

    const float* xp = xg + gcol;
    float* sp = Sg + gcol;
    float* op = xo + gcol;

    auto xld = [&](int r, int io) -> float {
        if (ER || EC) {
            bool ok = (!ER || (unsigned)r < (unsigned)IMG) && (!EC || colOK);
            float v = INF;
            if (ok) v = xp[r * IMG + io];
            return v;
        }
        return xp[r * IMG + io];     // interior: provably in-bounds
    };
    auto sld = [&](int r, int io) -> float {
        if (INIT) return 0.f;
        if (ER || EC) {
            bool ok = (!ER || (unsigned)r < (unsigned)IMG) && (!EC || colOK);
            float v = 0.f;
            if (ok) v = sp[r * IMG + io];
            return v;
        }
        return sp[r * IMG + io];
    };

    #pragma unroll
    for (int i = 0; i < C; ++i) { XQa[i] = xld(t0 + i, 0); XQb[i] = xld(t0 + i, IOFF); }
    #pragma unroll
    for (int i = 0; i < C; ++i) {
        SQa[i] = INIT ? 0.f : sld(t0 - 1 + i, 0);
        SQb[i] = INIT ? 0.f : sld(t0 - 1 + i, IOFF);
    }

    for (int kk = 0; kk < NSTEPS; kk += INNER) {       // rolled outer loop
        #pragma unroll
        for (int j = 0; j < INNER; ++j) {              // fully unrolled: j static
            const int k = kk + j;
            const int t = t0 + k;
            const int qi = j % C;                      // static
            float Cin0 = XQa[qi], Cin1 = XQb[qi];      // x_0 row t, both images
            XQa[qi] = xld(t + C, 0);                   // prefetch depth C
            XQb[qi] = xld(t + C, IOFF);
            float sn0 = SQa[qi], sn1 = SQb[qi];        // s row t-1
            if (!INIT) { SQa[qi] = sld(t + C - 1, 0); SQb[qi] = sld(t + C - 1, IOFF); }

            #pragma unroll
            for (int l = 0; l < C; ++l) {
                const int bp = (T0PAR + j + l + 1) & 1;  // parity of row t-l-1
                const bool rok = !ER || ((unsigned)(t - l - 1) < (unsigned)IMG);
                float A0 = Wa[l][bp ^ 1], B0 = Wa[l][bp];
                float A1 = Wb[l][bp ^ 1], B1 = Wb[l][bp];
                float e0 = fminf(fminf(A0, Cin0), B0);
                e0 = fminf(e0, dpp_a(B0));  e0 = fminf(e0, dpp_b(B0));
                float e1 = fminf(fminf(A1, Cin1), B1);
                e1 = fminf(e1, dpp_a(B1));  e1 = fminf(e1, dpp_b(B1));
                if (ER) { e0 = rok ? e0 : INF;  e1 = rok ? e1 : INF; }
                float xd0 = e0, xd1 = e1;
                if (EC) {
                    xd0 = colOK ? e0 : -INF;  e0 = colOK ? e0 : INF;
                    xd1 = colOK ? e1 : -INF;  e1 = colOK ? e1 : INF;
                }
                float hm0 = fmaxf(xd0, fmaxf(dpp_a(xd0), dpp_b(xd0)));
                float hm1 = fmaxf(xd1, fmaxf(dpp_a(xd1), dpp_b(xd1)));
                if (ER) { hm0 = rok ? hm0 : -INF;  hm1 = rok ? hm1 : -INF; }
                float dil0 = fmaxf(fmaxf(Ha[l][bp], Ha[l][bp ^ 1]), hm0);
                float dil1 = fmaxf(fmaxf(Hb[l][bp], Hb[l][bp ^ 1]), hm1);
                float d0 = fmaxf(A0 - dil0, 0.f);
                float d1 = fmaxf(A1 - dil1, 0.f);
                const int si = (l + C - qi) % C;         // SK slot of stage l (static)
                float s0 = SKa[si]; SKa[si] = (s0 + d0) - s0 * d0;
                float s1 = SKb[si]; SKb[si] = (s1 + d1) - s1 * d1;
                Wa[l][bp ^ 1] = Cin0;  Wb[l][bp ^ 1] = Cin1;
                Ha[l][bp] = hm0;       Hb[l][bp] = hm1;
                Cin0 = e0;  Cin1 = e1;                   // feed next level
            }

            // stores: x_C row t-C, skel row t-C-1 (wave-uniform k-guards)
            if (!LAST) {
                if ((unsigned)(k - XS0) < BH) {
                    if (owned) {
                        op[(t - C) * IMG]        = Cin0;
                        op[(t - C) * IMG + IOFF] = Cin1;
                    }
                }
            }
            if ((unsigned)(k - SS0) < BH) {
                const int so = (2 * C - 1 - qi) % C;     // stage C-1 slot (static)
                if (owned) {
                    sp[(t - C - 1) * IMG]        = SKa[so];
                    sp[(t - C - 1) * IMG + IOFF] = SKb[so];
                }
            }
            // insert s[t-1] at next step's stage-0 slot (== retiring stage C-1 slot)
            const int ins = (C - ((j + 1) % C)) % C;
            SKa[ins] = sn0;  SKb[ins] = sn1;
        }
    }
}

template<int C, bool INIT, bool LAST>
__global__ __launch_bounds__(256) void fused_pipe(const float* __restrict__ xin,
                                                  float* __restrict__ xout,
                                                  float* __restrict__ S)
{
    constexpr int OW = 64 - 2 * (C + 1);                 // owned cols per wave
    constexpr int NSTRIP = (IMG + OW - 1) / OW;          // 11 (C=6), 10 (C=3)
    const int lane = threadIdx.x & 63;
    const int task = blockIdx.x * 4 + (threadIdx.x >> 6);
    const int strip = task % NSTRIP;
    const int rem = task / NSTRIP;
    const int band = rem % NBANDS;
    const int pair = rem / NBANDS;                       // image pair: (pair, pair+8)
    const int R0 = band * BH;
    const int gcol = strip * OW - (C + 1) + lane;
    const bool colOK = (unsigned)gcol < (unsigned)IMG;
    const bool owned = (lane >= C + 1) && (lane < C + 1 + OW) && colOK;
    const float* xg = xin + (size_t)pair * PS;
    float* xo = xout + (size_t)pair * PS;
    float* Sg = S + (size_t)pair * PS;
    const bool erow = (band == 0) || (band == NBANDS - 1);
    const bool ecol = (strip == 0) || (strip * OW - (C + 1) + 63 >= IMG);

    if (erow) {
        if (ecol) pipe_run<C, true , true , INIT, LAST>(xg, xo, Sg, R0, gcol, colOK, owned);
        else      pipe_run<C, true , false, INIT, LAST>(xg, xo, Sg, R0, gcol, colOK, owned);
    } else {
        if (ecol) pipe_run<C, false, true , INIT, LAST>(xg, xo, Sg, R0, gcol, colOK, owned);
        else      pipe_run<C, false, false, INIT, LAST>(xg, xo, Sg, R0, gcol, colOK, owned);
    }
}

// ---- reduction: per-block partials, no global atomics ----
__global__ __launch_bounds__(256) void reduce_kernel(const float* __restrict__ logits,
                                                     const float* __restrict__ target,
                                                     const float* __restrict__ S,
                                                     float* __restrict__ partial)
{
    const int sample = blockIdx.y;
    const size_t base = (size_t)sample * PS;
    const float4* p4  = (const float4*)(logits + base);
    const float4* t4  = (const float4*)(target + base);
    const float4* sp4 = (const float4*)(S + base);
    const float4* sl4 = (const float4*)(S + (size_t)NSAMP * PS + base);
    float v[7] = {0.f, 0.f, 0.f, 0.f, 0.f, 0.f, 0.f};
    const int n4 = PS / 4;
    for (int i = blockIdx.x * 256 + threadIdx.x; i < n4; i += 32 * 256) {
        float4 L = p4[i], Tt = t4[i], SP = sp4[i], SL = sl4[i];
        float p;
        p = sigm(L.x); v[0] += SP.x * Tt.x; v[1] += SP.x; v[2] += SL.x * p; v[3] += SL.x; v[4] += p * Tt.x; v[5] += p; v[6] += Tt.x;
        p = sigm(L.y); v[0] += SP.y * Tt.y; v[1] += SP.y; v[2] += SL.y * p; v[3] += SL.y; v[4] += p * Tt.y; v[5] += p; v[6] += Tt.y;
        p = sigm(L.z); v[0] += SP.z * Tt.z; v[1] += SP.z; v[2] += SL.z * p; v[3] += SL.z; v[4] += p * Tt.z; v[5] += p; v[6] += Tt.z;
        p = sigm(L.w); v[0] += SP.w * Tt.w; v[1] += SP.w; v[2] += SL.w * p; v[3] += SL.w; v[4] += p * Tt.w; v[5] += p; v[6] += Tt.w;
    }
    #pragma unroll
    for (int off = 32; off > 0; off >>= 1)
        #pragma unroll
        for (int q = 0; q < 7; ++q) v[q] += __shfl_down(v[q], off);
    __shared__ float wred[4][7];
    int lane = threadIdx.x & 63, w = threadIdx.x >> 6;
    if (lane == 0)
        #pragma unroll
        for (int q = 0; q < 7; ++q) wred[w][q] = v[q];
    __syncthreads();
    if (threadIdx.x == 0) {
        #pragma unroll
        for (int q = 0; q < 7; ++q)
            partial[(sample * 32 + blockIdx.x) * 7 + q] =
                wred[0][q] + wred[1][q] + wred[2][q] + wred[3][q];
    }
}

__global__ __launch_bounds__(256) void final_kernel(const float* __restrict__ partial,
                                                    float* __restrict__ out)
{
    const int t = threadIdx.x;
    const int sample = t >> 5, part = t & 31;
    float v[7];
    #pragma unroll
    for (int q = 0; q < 7; ++q) v[q] = partial[(sample * 32 + part) * 7 + q];
    #pragma unroll
    for (int off = 16; off > 0; off >>= 1)
        #pragma unroll
        for (int q = 0; q < 7; ++q) v[q] += __shfl_down(v[q], off, 32);
    __shared__ float acc[NSAMP][7];
    if (part == 0)
        #pragma unroll
        for (int q = 0; q < 7; ++q) acc[sample][q] = v[q];
    __syncthreads();
    if (t == 0) {
        float cl = 0.f, dice = 0.f;
        for (int n = 0; n < NSAMP; n++) {
            float A = acc[n][0], Bv = acc[n][1], Cc = acc[n][2], D = acc[n][3];
            float E = acc[n][4], F = acc[n][5], G = acc[n][6];
            float tprec = (A + 1.0f) / (Bv + 1.0f);
            float tsens = (Cc + 1.0f) / (D + 1.0f);
            cl   += 1.0f - 2.0f * tprec * tsens / (tprec + tsens);
            dice += 1.0f - 2.0f * (E + 1.0f) / (F + G + 1.0f);
        }
        out[0] = 0.7f * (dice / NSAMP) + 0.3f * (cl / NSAMP);
    }
}

extern "C" void kernel_launch(void* const* d_in, const int* in_sizes, int n_in,
                              void* d_out, int out_size, void* d_ws, size_t ws_size,
                              hipStream_t stream)
{
    const float* logits = (const float*)d_in[0];
    const float* target = (const float*)d_in[1];
    float* out = (float*)d_out;

    const size_t NTOT = (size_t)NIMG * PS;
    float* Xa = (float*)d_ws;                       // Xa | Xb | S | partial
    float* Xb = Xa + NTOT;
    float* S  = Xb + NTOT;
    float* partial = S + NTOT;                      // 256*7 floats

    const int n4 = (NSAMP * PS) / 4;
    prep_kernel<<<n4 / 256, 256, 0, stream>>>((const float4*)logits, (const float4*)target,
                                              (float4*)Xa, n4);

    // 51 levels = 6 (INIT) + 7*6 + 3 (LAST). blocks = NSTRIP*NBANDS*NPAIR/4.
    const int B6 = 11 * NBANDS * NPAIR / 4;         // 704 blocks (2816 waves)
    const int B3 = 10 * NBANDS * NPAIR / 4;         // 640 blocks (2560 waves)
    fused_pipe<6, true , false><<<B6, 256, 0, stream>>>(Xa, Xb, S);
    fused_pipe<6, false, false><<<B6, 256, 0, stream>>>(Xb, Xa, S);
    fused_pipe<6, false, false><<<B6, 256, 0, stream>>>(Xa, Xb, S);
    fused_pipe<6, false, false><<<B6, 256, 0, stream>>>(Xb, Xa, S);
    fused_pipe<6, false, false><<<B6, 256, 0, stream>>>(Xa, Xb, S);
    fused_pipe<6, false, false><<<B6, 256, 0, stream>>>(Xb, Xa, S);
    fused_pipe<6, false, false><<<B6, 256, 0, stream>>>(Xa, Xb, S);
    fused_pipe<6, false, false><<<B6, 256, 0, stream>>>(Xb, Xa, S);
    fused_pipe<3, false, true ><<<B3, 256, 0, stream>>>(Xa, Xb, S);   // last: skip dead x-write

    reduce_kernel<<<dim3(32, NSAMP), 256, 0, stream>>>(logits, target, S, partial);
    final_kernel<<<1, 256, 0, stream>>>(partial, out);
}

// Round 11
// 371.513 us; speedup vs baseline: 1.2841x; 1.2550x over previous
//
#include <hip/hip_runtime.h>
#include <math.h>

// Problem: N=8, C=1, H=W=512 fp32. 16 images (8 sigmoid + 8 target) skeletonized.
// R7-R10 calibration: dur ~= total VALU instr x ~4.3 cyc (VALUBusy pinned ~40%
// for any TLP/ILP arrangement) -> minimize instructions+bytes: packed f16 pairs.
#define IMG   512
#define NSAMP 8
#define NIMG  16
#define PS    (IMG * IMG)

#define NBANDS 32
#define BH     (IMG / NBANDS)   // 16 (R0 even -> static parities; PAD=0 for C=6,3)
#define HALOC  8                // column halo in cols (even, >= C+1)
#define OW     112              // owned cols/wave = 128 - 2*HALOC
#define NSTRIP 5                // ceil(512/112); strips tile [strip*112, +112)

typedef _Float16 h2 __attribute__((ext_vector_type(2)));
typedef _Float16 h4 __attribute__((ext_vector_type(4)));
typedef unsigned int u32;

__device__ __forceinline__ float sigm(float x) { return 1.0f / (1.0f + expf(-x)); }

__device__ __forceinline__ h2 h2min(h2 a, h2 b) { return __builtin_elementwise_min(a, b); }
__device__ __forceinline__ h2 h2max(h2 a, h2 b) { return __builtin_elementwise_max(a, b); }
__device__ __forceinline__ u32 bc32(h2 v) { return __builtin_bit_cast(u32, v); }
__device__ __forceinline__ h2 bch2(u32 v) { return __builtin_bit_cast(h2, v); }

// lane shifts (wave_shl1 / wave_shr1), zeros shifted in (contained in halo)
__device__ __forceinline__ u32 dpp_a(u32 x) {   // x[i+1]
    return __builtin_amdgcn_update_dpp(0, (int)x, 0x130, 0xF, 0xF, true);
}
__device__ __forceinline__ u32 dpp_b(u32 x) {   // x[i-1]
    return __builtin_amdgcn_update_dpp(0, (int)x, 0x138, 0xF, 0xF, true);
}
// left-neighbor pair of (c0,c1) = (c_-1, c0); right-neighbor pair = (c1, c2)
__device__ __forceinline__ h2 shL(h2 own) {
    u32 o = bc32(own);
    return bch2(__builtin_amdgcn_alignbit(o, dpp_b(o), 16));
}
__device__ __forceinline__ h2 shR(h2 own) {
    u32 o = bc32(own);
    return bch2(__builtin_amdgcn_alignbit(dpp_a(o), o, 16));
}

// ---- prep: X[0:n]=sigmoid(logits) (f16), X[n:2n]=target (f16) ----
__global__ __launch_bounds__(256) void prep_kernel(const float4* __restrict__ lg,
                                                   const float4* __restrict__ tg,
                                                   h4* __restrict__ X, int n4)
{
    int i = blockIdx.x * 256 + threadIdx.x;
    if (i < n4) {
        float4 L = lg[i];
        h4 o; o[0] = (_Float16)sigm(L.x); o[1] = (_Float16)sigm(L.y);
              o[2] = (_Float16)sigm(L.z); o[3] = (_Float16)sigm(L.w);
        X[i] = o;
        float4 T = tg[i];
        h4 t; t[0] = (_Float16)T.x; t[1] = (_Float16)T.y;
              t[2] = (_Float16)T.z; t[3] = (_Float16)T.w;
        X[i + n4] = t;
    }
}

// ---- register line-pipeline, packed f16 (2 cols/lane), C fused levels ----
// Level l at step t: e = cross-erode(x_l) -> x_{l+1}[t-l-1]; hm = rowmax3;
// dil = max3(hm history); d = relu(x_l[t-l-2]-dil); skel s' = s+d-s*d.
// min/max exact in f16; static renaming under INNER unroll (proven R7).
// NOTE (R6): never cap occupancy via __launch_bounds__ 2nd arg (spill disaster).
template<int C, bool ER, bool EC, bool INIT, bool LAST>
__device__ __forceinline__ void pipe_run(const _Float16* __restrict__ xg,
                                         _Float16* __restrict__ xo,
                                         _Float16* __restrict__ Sg,
                                         int R0, int gc, bool colOK, bool owned)
{
    const _Float16 HINF = (_Float16)__builtin_huge_valf();
    const h2 INF2  = (h2){ HINF,  HINF};
    const h2 NINF2 = (h2){-HINF, -HINF};
    const h2 Z2    = (h2){(_Float16)0.f, (_Float16)0.f};
    constexpr int RAW    = BH + 2 * C + 2;
    constexpr int INNER  = (C % 2 == 0) ? C : 2 * C;
    constexpr int NSTEPS = ((RAW + INNER - 1) / INNER) * INNER;
    constexpr int PAD    = NSTEPS - RAW;
    constexpr int T0PAR  = (C + 1 + PAD) & 1;     // parity of t0 (R0 even)
    constexpr int XS0    = 2 * C + 1 + PAD;       // k-window start for x stores
    constexpr int SS0    = 2 * C + 2 + PAD;       // k-window start for skel stores
    const int t0 = R0 - C - 1 - PAD;

    h2 W[C][2], HM[C][2], SK[C], XQ[C], SQ[C];
    #pragma unroll
    for (int l = 0; l < C; ++l) {
        W[l][0] = INF2;  W[l][1] = INF2;
        HM[l][0] = NINF2; HM[l][1] = NINF2;
        SK[l] = Z2;
    }

    const _Float16* xp = xg + gc;
    _Float16* sp = Sg + gc;
    _Float16* op = xo + gc;

    auto xld = [&](int r) -> h2 {
        if (ER || EC) {
            bool ok = (!ER || (unsigned)r < (unsigned)IMG) && (!EC || colOK);
            h2 v = INF2;
            if (ok) v = *(const h2*)(xp + r * IMG);
            return v;
        }
        return *(const h2*)(xp + r * IMG);   // interior: provably in-bounds
    };
    auto sld = [&](int r) -> h2 {
        if (INIT) return Z2;
        if (ER || EC) {
            bool ok = (!ER || (unsigned)r < (unsigned)IMG) && (!EC || colOK);
            h2 v = Z2;
            if (ok) v = *(const h2*)(sp + r * IMG);
            return v;
        }
        return *(const h2*)(sp + r * IMG);
    };

    #pragma unroll
    for (int i = 0; i < C; ++i) XQ[i] = xld(t0 + i);
    #pragma unroll
    for (int i = 0; i < C; ++i) SQ[i] = INIT ? Z2 : sld(t0 - 1 + i);

    for (int kk = 0; kk < NSTEPS; kk += INNER) {       // rolled outer loop
        #pragma unroll
        for (int j = 0; j < INNER; ++j) {              // fully unrolled: j static
            const int k = kk + j;
            const int t = t0 + k;
            const int qi = j % C;                      // static
            h2 Cin = XQ[qi];                           // x_0 row t
            XQ[qi] = xld(t + C);                       // prefetch depth C
            h2 snew = SQ[qi];                          // s row t-1
            if (!INIT) SQ[qi] = sld(t + C - 1);

            #pragma unroll
            for (int l = 0; l < C; ++l) {
                const int bp = (T0PAR + j + l + 1) & 1;  // parity of row t-l-1
                const bool rok = !ER || ((unsigned)(t - l - 1) < (unsigned)IMG);
                h2 A = W[l][bp ^ 1];                     // x_l row t-l-2
                h2 B = W[l][bp];                         // x_l row t-l-1
                h2 e = h2min(h2min(h2min(A, Cin), B), h2min(shL(B), shR(B)));
                if (ER) e = rok ? e : INF2;
                h2 xd = e;
                if (EC) { xd = colOK ? e : NINF2;  e = colOK ? e : INF2; }
                h2 hm = h2max(xd, h2max(shL(xd), shR(xd)));
                if (ER) hm = rok ? hm : NINF2;
                h2 dil = h2max(h2max(HM[l][bp], HM[l][bp ^ 1]), hm);
                h2 d = h2max(A - dil, Z2);
                const int si = (l + C - qi) % C;         // SK slot of stage l (static)
                h2 s = SK[si];
                SK[si] = (s + d) - s * d;
                W[l][bp ^ 1] = Cin;                      // row t-l overwrites t-l-2
                HM[l][bp] = hm;                          // row t-l-1 overwrites t-l-3
                Cin = e;                                 // feed next level
            }

            // stores: x_C row t-C, skel row t-C-1 (wave-uniform k-guards)
            if (!LAST) {
                if ((unsigned)(k - XS0) < BH) {
                    if (owned) *(h2*)(op + (t - C) * IMG) = Cin;
                }
            }
            if ((unsigned)(k - SS0) < BH) {
                const int so = (2 * C - 1 - qi) % C;     // stage C-1 slot (static)
                if (owned) *(h2*)(sp + (t - C - 1) * IMG) = SK[so];
            }
            // insert s[t-1] at next step's stage-0 slot (== retiring stage C-1 slot)
            SK[(C - ((j + 1) % C)) % C] = snew;
        }
    }
}

template<int C, bool INIT, bool LAST>
__global__ __launch_bounds__(256) void fused_pipe(const _Float16* __restrict__ xin,
                                                  _Float16* __restrict__ xout,
                                                  _Float16* __restrict__ S)
{
    const int lane = threadIdx.x & 63;
    const int task = blockIdx.x * 4 + (threadIdx.x >> 6);
    const int strip = task % NSTRIP;
    const int rem = task / NSTRIP;
    const int band = rem % NBANDS;
    const int img = rem / NBANDS;
    const int R0 = band * BH;
    const int gc = strip * OW - HALOC + 2 * lane;        // even; lane owns (gc, gc+1)
    const bool colOK = (unsigned)gc < (unsigned)IMG;     // pair-uniform
    const bool owned = (lane >= HALOC / 2) && (lane < 64 - HALOC / 2) && colOK;
    const _Float16* xg = xin + (size_t)img * PS;
    _Float16* xo = xout + (size_t)img * PS;
    _Float16* Sg = S + (size_t)img * PS;
    const bool erow = (band == 0) || (band == NBANDS - 1);
    const bool ecol = (strip == 0) || (strip * OW - HALOC + 127 >= IMG);

    if (erow) {
        if (ecol) pipe_run<C, true , true , INIT, LAST>(xg, xo, Sg, R0, gc, colOK, owned);
        else      pipe_run<C, true , false, INIT, LAST>(xg, xo, Sg, R0, gc, colOK, owned);
    } else {
        if (ecol) pipe_run<C, false, true , INIT, LAST>(xg, xo, Sg, R0, gc, colOK, owned);
        else      pipe_run<C, false, false, INIT, LAST>(xg, xo, Sg, R0, gc, colOK, owned);
    }
}

// ---- reduction: per-block partials, no global atomics (S is f16) ----
__global__ __launch_bounds__(256) void reduce_kernel(const float* __restrict__ logits,
                                                     const float* __restrict__ target,
                                                     const _Float16* __restrict__ S,
                                                     float* __restrict__ partial)
{
    const int sample = blockIdx.y;
    const size_t base = (size_t)sample * PS;
    const float4* p4  = (const float4*)(logits + base);
    const float4* t4  = (const float4*)(target + base);
    const h4* sp4 = (const h4*)(S + base);
    const h4* sl4 = (const h4*)(S + (size_t)NSAMP * PS + base);
    float v[7] = {0.f, 0.f, 0.f, 0.f, 0.f, 0.f, 0.f};
    const int n4 = PS / 4;
    for (int i = blockIdx.x * 256 + threadIdx.x; i < n4; i += 32 * 256) {
        float4 L = p4[i], Tt = t4[i];
        h4 SPh = sp4[i], SLh = sl4[i];
        float p, sp_, sl_;
        p = sigm(L.x); sp_ = (float)SPh[0]; sl_ = (float)SLh[0];
        v[0] += sp_ * Tt.x; v[1] += sp_; v[2] += sl_ * p; v[3] += sl_; v[4] += p * Tt.x; v[5] += p; v[6] += Tt.x;
        p = sigm(L.y); sp_ = (float)SPh[1]; sl_ = (float)SLh[1];
        v[0] += sp_ * Tt.y; v[1] += sp_; v[2] += sl_ * p; v[3] += sl_; v[4] += p * Tt.y; v[5] += p; v[6] += Tt.y;
        p = sigm(L.z); sp_ = (float)SPh[2]; sl_ = (float)SLh[2];
        v[0] += sp_ * Tt.z; v[1] += sp_; v[2] += sl_ * p; v[3] += sl_; v[4] += p * Tt.z; v[5] += p; v[6] += Tt.z;
        p = sigm(L.w); sp_ = (float)SPh[3]; sl_ = (float)SLh[3];
        v[0] += sp_ * Tt.w; v[1] += sp_; v[2] += sl_ * p; v[3] += sl_; v[4] += p * Tt.w; v[5] += p; v[6] += Tt.w;
    }
    #pragma unroll
    for (int off = 32; off > 0; off >>= 1)
        #pragma unroll
        for (int q = 0; q < 7; ++q) v[q] += __shfl_down(v[q], off);
    __shared__ float wred[4][7];
    int lane = threadIdx.x & 63, w = threadIdx.x >> 6;
    if (lane == 0)
        #pragma unroll
        for (int q = 0; q < 7; ++q) wred[w][q] = v[q];
    __syncthreads();
    if (threadIdx.x == 0) {
        #pragma unroll
        for (int q = 0; q < 7; ++q)
            partial[(sample * 32 + blockIdx.x) * 7 + q] =
                wred[0][q] + wred[1][q] + wred[2][q] + wred[3][q];
    }
}

__global__ __launch_bounds__(256) void final_kernel(const float* __restrict__ partial,
                                                    float* __restrict__ out)
{
    const int t = threadIdx.x;
    const int sample = t >> 5, part = t & 31;
    float v[7];
    #pragma unroll
    for (int q = 0; q < 7; ++q) v[q] = partial[(sample * 32 + part) * 7 + q];
    #pragma unroll
    for (int off = 16; off > 0; off >>= 1)
        #pragma unroll
        for (int q = 0; q < 7; ++q) v[q] += __shfl_down(v[q], off, 32);
    __shared__ float acc[NSAMP][7];
    if (part == 0)
        #pragma unroll
        for (int q = 0; q < 7; ++q) acc[sample][q] = v[q];
    __syncthreads();
    if (t == 0) {
        float cl = 0.f, dice = 0.f;
        for (int n = 0; n < NSAMP; n++) {
            float A = acc[n][0], Bv = acc[n][1], Cc = acc[n][2], D = acc[n][3];
            float E = acc[n][4], F = acc[n][5], G = acc[n][6];
            float tprec = (A + 1.0f) / (Bv + 1.0f);
            float tsens = (Cc + 1.0f) / (D + 1.0f);
            cl   += 1.0f - 2.0f * tprec * tsens / (tprec + tsens);
            dice += 1.0f - 2.0f * (E + 1.0f) / (F + G + 1.0f);
        }
        out[0] = 0.7f * (dice / NSAMP) + 0.3f * (cl / NSAMP);
    }
}

extern "C" void kernel_launch(void* const* d_in, const int* in_sizes, int n_in,
                              void* d_out, int out_size, void* d_ws, size_t ws_size,
                              hipStream_t stream)
{
    const float* logits = (const float*)d_in[0];
    const float* target = (const float*)d_in[1];
    float* out = (float*)d_out;

    const size_t NTOT = (size_t)NIMG * PS;          // halves per buffer
    _Float16* Xa = (_Float16*)d_ws;                 // Xa | Xb | S | partial
    _Float16* Xb = Xa + NTOT;
    _Float16* S  = Xb + NTOT;
    float* partial = (float*)(S + NTOT);            // 256*7 floats (4B-aligned: NTOT even)

    const int n4 = (NSAMP * PS) / 4;
    prep_kernel<<<n4 / 256, 256, 0, stream>>>((const float4*)logits, (const float4*)target,
                                              (h4*)Xa, n4);

    // 51 levels = 6 (INIT) + 7*6 + 3 (LAST). blocks = NSTRIP*NBANDS*NIMG/4 = 640.
    const int B = NSTRIP * NBANDS * NIMG / 4;       // 640 blocks (2560 waves)
    fused_pipe<6, true , false><<<B, 256, 0, stream>>>(Xa, Xb, S);
    fused_pipe<6, false, false><<<B, 256, 0, stream>>>(Xb, Xa, S);
    fused_pipe<6, false, false><<<B, 256, 0, stream>>>(Xa, Xb, S);
    fused_pipe<6, false, false><<<B, 256, 0, stream>>>(Xb, Xa, S);
    fused_pipe<6, false, false><<<B, 256, 0, stream>>>(Xa, Xb, S);
    fused_pipe<6, false, false><<<B, 256, 0, stream>>>(Xb, Xa, S);
    fused_pipe<6, false, false><<<B, 256, 0, stream>>>(Xa, Xb, S);
    fused_pipe<6, false, false><<<B, 256, 0, stream>>>(Xb, Xa, S);
    fused_pipe<3, false, true ><<<B, 256, 0, stream>>>(Xa, Xb, S);   // last: skip dead x-write

    reduce_kernel<<<dim3(32, NSAMP), 256, 0, stream>>>(logits, target, S, partial);
    final_kernel<<<1, 256, 0, stream>>>(partial, out);
}